// Round 1
// baseline (1895.304 us; speedup 1.0000x reference)
//
#include <hip/hip_runtime.h>

// ---------------------------------------------------------------------------
// AttentionBlock: GroupNorm(32) -> q,k,v = xn@W+b -> softmax(q k^T / sqrt(C)) v
//                 -> out@wp+bp + x.   B=2, H=W=64, C=512, S=4096 per batch.
// Strategy round 1: correct bf16-MFMA implementation.
//   - all GEMMs via mfma_f32_16x16x32_bf16 with verified layouts:
//       A-frag: A[m=lane&15][k=(lane>>4)*8+j]  (16B contiguous when A row-major)
//       B-frag: B[k=(lane>>4)*8+j][n=lane&15]  (16B contiguous when B^T row-major)
//       C/D   : col=lane&15, row=(lane>>4)*4+reg
//   - attention: flash-style online softmax, 16 Q-rows/wave, 32-key tiles,
//     P transformed C->A layout through LDS.
// ---------------------------------------------------------------------------

typedef __bf16 bf16_t;
typedef __bf16 bf16x8 __attribute__((ext_vector_type(8)));
typedef __bf16 bf16x4 __attribute__((ext_vector_type(4)));
typedef float  f32x4  __attribute__((ext_vector_type(4)));

__device__ __forceinline__ bf16x8 ld8(const bf16_t* p) {
    return *reinterpret_cast<const bf16x8*>(p);
}
__device__ __forceinline__ f32x4 mfma16(bf16x8 a, bf16x8 b, f32x4 c) {
    return __builtin_amdgcn_mfma_f32_16x16x32_bf16(a, b, c, 0, 0, 0);
}

#define NPIX 8192      // B*H*W
#define C512 512
#define SEQ  4096      // H*W per batch

// ---------------- GroupNorm stats: one block per (b,g), 64 blocks -----------
__global__ __launch_bounds__(256) void gn_stats_k(const float* __restrict__ x,
                                                  float* __restrict__ stats) {
    int bg = blockIdx.x;               // b*32+g
    int b  = bg >> 5, g = bg & 31;
    const float* xp = x + (size_t)b * SEQ * C512 + g * 16;
    float s = 0.f, s2 = 0.f;
    for (int p = threadIdx.x; p < SEQ; p += 256) {
        const float4* q = reinterpret_cast<const float4*>(xp + (size_t)p * C512);
        #pragma unroll
        for (int i = 0; i < 4; i++) {
            float4 v = q[i];
            s  += v.x + v.y + v.z + v.w;
            s2 += v.x*v.x + v.y*v.y + v.z*v.z + v.w*v.w;
        }
    }
    #pragma unroll
    for (int off = 32; off >= 1; off >>= 1) {
        s  += __shfl_down(s, off);
        s2 += __shfl_down(s2, off);
    }
    __shared__ float rs[4], rs2[4];
    int wave = threadIdx.x >> 6;
    if ((threadIdx.x & 63) == 0) { rs[wave] = s; rs2[wave] = s2; }
    __syncthreads();
    if (threadIdx.x == 0) {
        float S = 0.f, S2 = 0.f;
        for (int i = 0; i < 4; i++) { S += rs[i]; S2 += rs2[i]; }
        float mean = S * (1.f / 65536.f);
        float var  = S2 * (1.f / 65536.f) - mean * mean;
        stats[bg * 2]     = mean;
        stats[bg * 2 + 1] = rsqrtf(var + 1e-5f);
    }
}

// ---------------- weights: fp32 (k,n) -> bf16 transposed (n,k) --------------
__global__ __launch_bounds__(256) void wt_conv_k(const float* w0, const float* w1,
                                                 const float* w2, const float* w3,
                                                 bf16_t* o0, bf16_t* o1,
                                                 bf16_t* o2, bf16_t* o3) {
    const float* w = (blockIdx.y == 0) ? w0 : (blockIdx.y == 1) ? w1
                   : (blockIdx.y == 2) ? w2 : w3;
    bf16_t* o = (blockIdx.y == 0) ? o0 : (blockIdx.y == 1) ? o1
              : (blockIdx.y == 2) ? o2 : o3;
    int tid = blockIdx.x * 256 + threadIdx.x;     // 262144 total
    int n = tid >> 9, k = tid & 511;
    o[(size_t)n * C512 + k] = (bf16_t)w[(size_t)k * C512 + n];
}

// ---------------- xn = groupnorm(x)*gamma+beta -> bf16 ----------------------
__global__ __launch_bounds__(256) void xn_k(const float* __restrict__ x,
                                            const float* __restrict__ stats,
                                            const float* __restrict__ gamma,
                                            const float* __restrict__ beta,
                                            bf16_t* __restrict__ xn) {
    size_t idx = ((size_t)blockIdx.x * 256 + threadIdx.x) * 4;   // elem index
    int c = (int)(idx & 511);
    size_t pix = idx >> 9;
    int b = (int)(pix >> 12);
    int g = c >> 4;
    float mean = stats[(b * 32 + g) * 2];
    float rstd = stats[(b * 32 + g) * 2 + 1];
    float4 v  = *reinterpret_cast<const float4*>(x + idx);
    float4 gm = *reinterpret_cast<const float4*>(gamma + c);
    float4 bt = *reinterpret_cast<const float4*>(beta + c);
    bf16x4 o;
    o[0] = (bf16_t)((v.x - mean) * rstd * gm.x + bt.x);
    o[1] = (bf16_t)((v.y - mean) * rstd * gm.y + bt.y);
    o[2] = (bf16_t)((v.z - mean) * rstd * gm.z + bt.z);
    o[3] = (bf16_t)((v.w - mean) * rstd * gm.w + bt.w);
    *reinterpret_cast<bf16x4*>(xn + idx) = o;
}

// ---------------- GEMM: D(M=8192,N=512) = A(bf16) x WT^T + bias -------------
// MODE 0: store bf16 row-major (Q,K)
// MODE 1: store bf16 transposed per batch: vt[b][n][s]  (V)
// MODE 2: store fp32 + residual (final projection)
template <int MODE>
__global__ __launch_bounds__(256) void gemm_k(const bf16_t* __restrict__ A,
                                              const bf16_t* __restrict__ WT,
                                              const float* __restrict__ bias,
                                              const float* __restrict__ resid,
                                              void* __restrict__ outp) {
    int lane = threadIdx.x & 63;
    int w    = threadIdx.x >> 6;          // 4 waves, 2x2
    int lrow = lane & 15, quad = lane >> 4;
    int mbase = blockIdx.x * 64 + (w & 1) * 32;
    int nbase = blockIdx.y * 64 + (w >> 1) * 32;

    f32x4 acc[2][2] = {};
    const bf16_t* a0p = A  + (size_t)(mbase + lrow) * C512 + quad * 8;
    const bf16_t* a1p = a0p + 16 * C512;
    const bf16_t* b0p = WT + (size_t)(nbase + lrow) * C512 + quad * 8;
    const bf16_t* b1p = b0p + 16 * C512;

    #pragma unroll 4
    for (int ks = 0; ks < 16; ks++) {
        bf16x8 a0 = ld8(a0p + ks * 32);
        bf16x8 a1 = ld8(a1p + ks * 32);
        bf16x8 b0 = ld8(b0p + ks * 32);
        bf16x8 b1 = ld8(b1p + ks * 32);
        acc[0][0] = mfma16(a0, b0, acc[0][0]);
        acc[0][1] = mfma16(a0, b1, acc[0][1]);
        acc[1][0] = mfma16(a1, b0, acc[1][0]);
        acc[1][1] = mfma16(a1, b1, acc[1][1]);
    }

    #pragma unroll
    for (int mi = 0; mi < 2; mi++) {
        #pragma unroll
        for (int ni = 0; ni < 2; ni++) {
            int col  = nbase + ni * 16 + lrow;
            float bv = bias[col];
            int rowb = mbase + mi * 16 + quad * 4;
            #pragma unroll
            for (int i = 0; i < 4; i++) {
                int row = rowb + i;
                float val = acc[mi][ni][i] + bv;
                if (MODE == 0) {
                    ((bf16_t*)outp)[(size_t)row * C512 + col] = (bf16_t)val;
                } else if (MODE == 1) {
                    int b = row >> 12, s = row & 4095;
                    ((bf16_t*)outp)[((size_t)(b * C512 + col)) * SEQ + s] = (bf16_t)val;
                } else {
                    size_t idx = (size_t)row * C512 + col;
                    ((float*)outp)[idx] = val + resid[idx];
                }
            }
        }
    }
}

// ---------------- flash attention: 1 wave / 16 Q-rows, 32-key tiles ---------
__global__ __launch_bounds__(64, 1) void attn_k(const bf16_t* __restrict__ Q,
                                                const bf16_t* __restrict__ K,
                                                const bf16_t* __restrict__ VT,
                                                bf16_t* __restrict__ O) {
    __shared__ bf16_t pl[16 * 32];
    int lane = threadIdx.x;
    int lrow = lane & 15, quad = lane >> 4;
    int b  = blockIdx.x >> 8;            // 256 q-tiles per batch
    int qt = blockIdx.x & 255;
    size_t qrow = (size_t)b * SEQ + qt * 16;

    // Q fragments held in registers for the whole key sweep (64 VGPRs)
    bf16x8 qf[16];
    const bf16_t* qp = Q + (qrow + lrow) * C512 + quad * 8;
    #pragma unroll
    for (int ks = 0; ks < 16; ks++) qf[ks] = ld8(qp + ks * 32);

    f32x4 acc[32] = {};                  // O accumulator: 16 rows x 512 cols
    float mst[4] = {-1e30f, -1e30f, -1e30f, -1e30f};
    float lst[4] = {0.f, 0.f, 0.f, 0.f};
    const float scale = 0.044194173824159216f;   // 512^-0.5

    const bf16_t* kbasep = K  + ((size_t)b * SEQ + lrow) * C512 + quad * 8;
    const bf16_t* vbasep = VT + ((size_t)b * C512 + lrow) * SEQ + quad * 8;

    for (int kt = 0; kt < 128; kt++) {
        // ---- S = Q K^T for 32 keys (two 16x16 n-tiles) ----
        f32x4 s0 = {}, s1 = {};
        const bf16_t* kp0 = kbasep + (size_t)(kt * 32) * C512;
        const bf16_t* kp1 = kp0 + 16 * C512;
        #pragma unroll 4
        for (int ks = 0; ks < 16; ks++) {
            s0 = mfma16(qf[ks], ld8(kp0 + ks * 32), s0);
            s1 = mfma16(qf[ks], ld8(kp1 + ks * 32), s1);
        }
        // ---- online softmax update (rows live on 16 lanes of each quad) ----
        float p0[4], p1[4], alpha[4];
        #pragma unroll
        for (int i = 0; i < 4; i++) {
            float v0 = s0[i] * scale, v1 = s1[i] * scale;
            float mx = fmaxf(v0, v1);
            #pragma unroll
            for (int d = 8; d >= 1; d >>= 1) mx = fmaxf(mx, __shfl_xor(mx, d));
            float mnew = fmaxf(mst[i], mx);
            alpha[i] = __expf(mst[i] - mnew);
            p0[i] = __expf(v0 - mnew);
            p1[i] = __expf(v1 - mnew);
            float rsum = p0[i] + p1[i];
            #pragma unroll
            for (int d = 8; d >= 1; d >>= 1) rsum += __shfl_xor(rsum, d);
            lst[i] = lst[i] * alpha[i] + rsum;
            mst[i] = mnew;
        }
        #pragma unroll
        for (int n = 0; n < 32; n++)
            #pragma unroll
            for (int i = 0; i < 4; i++) acc[n][i] *= alpha[i];

        // ---- P: C-layout -> A-layout through LDS ----
        __syncthreads();   // WAR: previous iteration's reads done
        #pragma unroll
        for (int i = 0; i < 4; i++) {
            pl[(quad * 4 + i) * 32 + lrow]      = (bf16_t)p0[i];
            pl[(quad * 4 + i) * 32 + 16 + lrow] = (bf16_t)p1[i];
        }
        __syncthreads();
        bf16x8 pf = *reinterpret_cast<const bf16x8*>(&pl[lrow * 32 + quad * 8]);

        // ---- O += P V  (32 n-tiles over the 512 channels) ----
        const bf16_t* vp = vbasep + kt * 32;
        #pragma unroll 8
        for (int n = 0; n < 32; n++)
            acc[n] = mfma16(pf, ld8(vp + (size_t)n * 16 * SEQ), acc[n]);
    }

    // ---- normalize and store bf16 row-major ----
    #pragma unroll
    for (int n = 0; n < 32; n++) {
        int c = n * 16 + lrow;
        #pragma unroll
        for (int i = 0; i < 4; i++) {
            float val = acc[n][i] / lst[i];
            O[(qrow + quad * 4 + i) * C512 + c] = (bf16_t)val;
        }
    }
}

// ---------------------------------------------------------------------------
extern "C" void kernel_launch(void* const* d_in, const int* in_sizes, int n_in,
                              void* d_out, int out_size, void* d_ws, size_t ws_size,
                              hipStream_t stream) {
    const float* x     = (const float*)d_in[0];
    const float* gamma = (const float*)d_in[1];
    const float* beta  = (const float*)d_in[2];
    const float* wq = (const float*)d_in[3];  const float* bq = (const float*)d_in[4];
    const float* wk = (const float*)d_in[5];  const float* bk = (const float*)d_in[6];
    const float* wv = (const float*)d_in[7];  const float* bv = (const float*)d_in[8];
    const float* wp = (const float*)d_in[9];  const float* bp = (const float*)d_in[10];
    float* out = (float*)d_out;

    char* ws = (char*)d_ws;
    size_t off = 0;
    float* stats = (float*)(ws + off);            off += 1024;
    bf16_t* xn   = (bf16_t*)(ws + off);           off += (size_t)NPIX * C512 * 2;
    bf16_t* wqT  = (bf16_t*)(ws + off);           off += (size_t)C512 * C512 * 2;
    bf16_t* wkT  = (bf16_t*)(ws + off);           off += (size_t)C512 * C512 * 2;
    bf16_t* wvT  = (bf16_t*)(ws + off);           off += (size_t)C512 * C512 * 2;
    bf16_t* wpT  = (bf16_t*)(ws + off);           off += (size_t)C512 * C512 * 2;
    bf16_t* Qb   = (bf16_t*)(ws + off);           off += (size_t)NPIX * C512 * 2;
    bf16_t* Kb   = (bf16_t*)(ws + off);           off += (size_t)NPIX * C512 * 2;
    bf16_t* VTb  = (bf16_t*)(ws + off);           off += (size_t)NPIX * C512 * 2;
    bf16_t* Ob   = (bf16_t*)(ws + off);           off += (size_t)NPIX * C512 * 2;

    gn_stats_k<<<64, 256, 0, stream>>>(x, stats);
    wt_conv_k<<<dim3(1024, 4), 256, 0, stream>>>(wq, wk, wv, wp, wqT, wkT, wvT, wpT);
    xn_k<<<4096, 256, 0, stream>>>(x, stats, gamma, beta, xn);

    dim3 ggrid(128, 8);
    gemm_k<0><<<ggrid, 256, 0, stream>>>(xn, wqT, bq, nullptr, Qb);
    gemm_k<0><<<ggrid, 256, 0, stream>>>(xn, wkT, bk, nullptr, Kb);
    gemm_k<1><<<ggrid, 256, 0, stream>>>(xn, wvT, bv, nullptr, VTb);

    attn_k<<<512, 64, 0, stream>>>(Qb, Kb, VTb, Ob);

    gemm_k<2><<<ggrid, 256, 0, stream>>>(Ob, wpT, bp, x, out);
}

// Round 2
// 629.132 us; speedup vs baseline: 3.0126x; 3.0126x over previous
//
#include <hip/hip_runtime.h>

// ---------------------------------------------------------------------------
// AttentionBlock: GroupNorm(32) -> q,k,v = xn@W+b -> softmax(q k^T / sqrt(C)) v
//                 -> out@wp+bp + x.   B=2, H=W=64, C=512, S=4096 per batch.
// Round 2: fix attn_k scratch spill (was 3 GB scratch traffic -> 1700 us).
//   New attn: block=4 waves, Q-tile=32 (2 rowgroups x 2 channel halves),
//   per-wave acc = 64 VGPRs (no spill). K/V double-buffered in LDS via
//   global_load_lds (16B), fragment-major K layout + [ch][key] V layout
//   => all ds_read_b128 lane-sequential (0 bank conflicts). One barrier
//   per key-tile; prefetch overlaps compute. Scale folded into wq/bq.
// ---------------------------------------------------------------------------

typedef __bf16 bf16_t;
typedef __bf16 bf16x8 __attribute__((ext_vector_type(8)));
typedef __bf16 bf16x4 __attribute__((ext_vector_type(4)));
typedef float  f32x4  __attribute__((ext_vector_type(4)));

__device__ __forceinline__ bf16x8 ld8(const bf16_t* p) {
    return *reinterpret_cast<const bf16x8*>(p);
}
__device__ __forceinline__ f32x4 mfma16(bf16x8 a, bf16x8 b, f32x4 c) {
    return __builtin_amdgcn_mfma_f32_16x16x32_bf16(a, b, c, 0, 0, 0);
}
__device__ __forceinline__ void gload16(const bf16_t* gp, bf16_t* lp) {
    // HW semantics: LDS dest = uniform base + laneid*16B; gp is per-lane.
    __builtin_amdgcn_global_load_lds(
        (const __attribute__((address_space(1))) void*)gp,
        (__attribute__((address_space(3))) void*)lp, 16, 0, 0);
}

#define NPIX 8192      // B*H*W
#define C512 512
#define SEQ  4096      // H*W per batch
#define ATTN_LDS_BYTES (2*32768 + 2*32768 + 4*1024)   // K dbuf + V dbuf + P

// ---------------- GroupNorm stats: one block per (b,g), 64 blocks -----------
__global__ __launch_bounds__(256) void gn_stats_k(const float* __restrict__ x,
                                                  float* __restrict__ stats) {
    int bg = blockIdx.x;               // b*32+g
    int b  = bg >> 5, g = bg & 31;
    const float* xp = x + (size_t)b * SEQ * C512 + g * 16;
    float s = 0.f, s2 = 0.f;
    for (int p = threadIdx.x; p < SEQ; p += 256) {
        const float4* q = reinterpret_cast<const float4*>(xp + (size_t)p * C512);
        #pragma unroll
        for (int i = 0; i < 4; i++) {
            float4 v = q[i];
            s  += v.x + v.y + v.z + v.w;
            s2 += v.x*v.x + v.y*v.y + v.z*v.z + v.w*v.w;
        }
    }
    #pragma unroll
    for (int off = 32; off >= 1; off >>= 1) {
        s  += __shfl_down(s, off);
        s2 += __shfl_down(s2, off);
    }
    __shared__ float rs[4], rs2[4];
    int wave = threadIdx.x >> 6;
    if ((threadIdx.x & 63) == 0) { rs[wave] = s; rs2[wave] = s2; }
    __syncthreads();
    if (threadIdx.x == 0) {
        float S = 0.f, S2 = 0.f;
        for (int i = 0; i < 4; i++) { S += rs[i]; S2 += rs2[i]; }
        float mean = S * (1.f / 65536.f);
        float var  = S2 * (1.f / 65536.f) - mean * mean;
        stats[bg * 2]     = mean;
        stats[bg * 2 + 1] = rsqrtf(var + 1e-5f);
    }
}

// ---------------- weights: fp32 (k,n) -> bf16 transposed (n,k) --------------
// wq (blockIdx.y==0) additionally folded with softmax scale C^-0.5.
__global__ __launch_bounds__(256) void wt_conv_k(const float* w0, const float* w1,
                                                 const float* w2, const float* w3,
                                                 bf16_t* o0, bf16_t* o1,
                                                 bf16_t* o2, bf16_t* o3) {
    const float* w = (blockIdx.y == 0) ? w0 : (blockIdx.y == 1) ? w1
                   : (blockIdx.y == 2) ? w2 : w3;
    bf16_t* o = (blockIdx.y == 0) ? o0 : (blockIdx.y == 1) ? o1
              : (blockIdx.y == 2) ? o2 : o3;
    float scale = (blockIdx.y == 0) ? 0.044194173824159216f : 1.0f;
    int tid = blockIdx.x * 256 + threadIdx.x;     // 262144 total
    int n = tid >> 9, k = tid & 511;
    o[(size_t)n * C512 + k] = (bf16_t)(w[(size_t)k * C512 + n] * scale);
}

// ---------------- xn = groupnorm(x)*gamma+beta -> bf16 ----------------------
__global__ __launch_bounds__(256) void xn_k(const float* __restrict__ x,
                                            const float* __restrict__ stats,
                                            const float* __restrict__ gamma,
                                            const float* __restrict__ beta,
                                            bf16_t* __restrict__ xn) {
    size_t idx = ((size_t)blockIdx.x * 256 + threadIdx.x) * 4;   // elem index
    int c = (int)(idx & 511);
    size_t pix = idx >> 9;
    int b = (int)(pix >> 12);
    int g = c >> 4;
    float mean = stats[(b * 32 + g) * 2];
    float rstd = stats[(b * 32 + g) * 2 + 1];
    float4 v  = *reinterpret_cast<const float4*>(x + idx);
    float4 gm = *reinterpret_cast<const float4*>(gamma + c);
    float4 bt = *reinterpret_cast<const float4*>(beta + c);
    bf16x4 o;
    o[0] = (bf16_t)((v.x - mean) * rstd * gm.x + bt.x);
    o[1] = (bf16_t)((v.y - mean) * rstd * gm.y + bt.y);
    o[2] = (bf16_t)((v.z - mean) * rstd * gm.z + bt.z);
    o[3] = (bf16_t)((v.w - mean) * rstd * gm.w + bt.w);
    *reinterpret_cast<bf16x4*>(xn + idx) = o;
}

// ---------------- GEMM: D(M=8192,N=512) = A(bf16) x WT^T + bias*bmul --------
// MODE 0: store bf16 row-major (Q,K)
// MODE 1: store bf16 transposed per batch: vt[b][n][s]  (V)
// MODE 2: store fp32 + residual (final projection)
template <int MODE>
__global__ __launch_bounds__(256) void gemm_k(const bf16_t* __restrict__ A,
                                              const bf16_t* __restrict__ WT,
                                              const float* __restrict__ bias,
                                              float bmul,
                                              const float* __restrict__ resid,
                                              void* __restrict__ outp) {
    int lane = threadIdx.x & 63;
    int w    = threadIdx.x >> 6;          // 4 waves, 2x2
    int lrow = lane & 15, quad = lane >> 4;
    int mbase = blockIdx.x * 64 + (w & 1) * 32;
    int nbase = blockIdx.y * 64 + (w >> 1) * 32;

    f32x4 acc[2][2] = {};
    const bf16_t* a0p = A  + (size_t)(mbase + lrow) * C512 + quad * 8;
    const bf16_t* a1p = a0p + 16 * C512;
    const bf16_t* b0p = WT + (size_t)(nbase + lrow) * C512 + quad * 8;
    const bf16_t* b1p = b0p + 16 * C512;

    #pragma unroll 4
    for (int ks = 0; ks < 16; ks++) {
        bf16x8 a0 = ld8(a0p + ks * 32);
        bf16x8 a1 = ld8(a1p + ks * 32);
        bf16x8 b0 = ld8(b0p + ks * 32);
        bf16x8 b1 = ld8(b1p + ks * 32);
        acc[0][0] = mfma16(a0, b0, acc[0][0]);
        acc[0][1] = mfma16(a0, b1, acc[0][1]);
        acc[1][0] = mfma16(a1, b0, acc[1][0]);
        acc[1][1] = mfma16(a1, b1, acc[1][1]);
    }

    #pragma unroll
    for (int mi = 0; mi < 2; mi++) {
        #pragma unroll
        for (int ni = 0; ni < 2; ni++) {
            int col  = nbase + ni * 16 + lrow;
            float bv = bias[col] * bmul;
            int rowb = mbase + mi * 16 + quad * 4;
            #pragma unroll
            for (int i = 0; i < 4; i++) {
                int row = rowb + i;
                float val = acc[mi][ni][i] + bv;
                if (MODE == 0) {
                    ((bf16_t*)outp)[(size_t)row * C512 + col] = (bf16_t)val;
                } else if (MODE == 1) {
                    int b = row >> 12, s = row & 4095;
                    ((bf16_t*)outp)[((size_t)(b * C512 + col)) * SEQ + s] = (bf16_t)val;
                } else {
                    size_t idx = (size_t)row * C512 + col;
                    ((float*)outp)[idx] = val + resid[idx];
                }
            }
        }
    }
}

// ---------------- flash attention v2 ----------------------------------------
// Grid: 256 blocks = 2 batches x 128 Q-tiles of 32 rows. Block: 4 waves.
//   wave w: rowgroup rg=w>>1 (16 Q-rows), channel half=w&1 (256 of 512 V-chs).
// K-tile LDS layout (fragment-major): 16B chunk for (key, ch8) at chunk index
//   ((ch8>>2)*2 + (key>>4))*64 + (ch8&3)*16 + (key&15)  -> every S-step
//   ds_read_b128 is a lane-sequential 1KB wave read (0 conflicts).
// V-tile LDS layout: [ch][32 keys] -> PV reads also lane-sequential.
__global__ __launch_bounds__(256, 1) void attn_k(const bf16_t* __restrict__ Q,
                                                 const bf16_t* __restrict__ K,
                                                 const bf16_t* __restrict__ VT,
                                                 bf16_t* __restrict__ O) {
    extern __shared__ char smem[];
    bf16_t* kbuf = (bf16_t*)smem;                  // 2 x 16384 elems
    bf16_t* vbuf = (bf16_t*)(smem + 65536);        // 2 x 16384 elems
    bf16_t* pbuf = (bf16_t*)(smem + 131072);       // 4 waves x 512 elems

    int lane = threadIdx.x & 63;
    int w    = threadIdx.x >> 6;
    int rg   = w >> 1, half = w & 1;
    int lrow = lane & 15, quad = lane >> 4;
    int b  = blockIdx.x >> 7;
    int qt = blockIdx.x & 127;
    size_t qbase = (size_t)b * SEQ + qt * 32;

    const bf16_t* Kb = K  + (size_t)b * SEQ * C512;
    const bf16_t* Vb = VT + (size_t)b * C512 * SEQ;
    bf16_t* pw = pbuf + w * 512;

    // Q fragments for this wave's 16 rows (scale already folded into wq/bq)
    bf16x8 qf[16];
    {
        const bf16_t* qp = Q + (qbase + rg * 16 + lrow) * C512 + quad * 8;
        #pragma unroll
        for (int ks = 0; ks < 16; ks++) qf[ks] = ld8(qp + ks * 32);
    }

    // stage key-tile kt into buffer `buf` (wave issues its 8 K + 8 V chunks)
    auto stage = [&](int buf, int kt) {
        bf16_t* kd = kbuf + buf * 16384;
        bf16_t* vd = vbuf + buf * 16384;
        #pragma unroll
        for (int ii = 0; ii < 8; ii++) {
            int i = w * 8 + ii;                       // 0..31
            {   // K chunk-instr i: (ks = i>>1, nt = i&1)
                int ks = i >> 1, nt = i & 1;
                const bf16_t* gp = Kb + (size_t)(kt * 32 + nt * 16 + lrow) * C512
                                      + ks * 32 + quad * 8;
                gload16(gp, kd + i * 512);
            }
            {   // V chunk-instr i: 16 channels x 32 keys
                const bf16_t* gp = Vb + (size_t)(i * 16 + (lane >> 2)) * SEQ
                                      + kt * 32 + (lane & 3) * 8;
                gload16(gp, vd + i * 512);
            }
        }
    };

    f32x4 acc[16] = {};                 // 16 rows x 256 chs (this wave's half)
    float mst[4] = {-1e30f, -1e30f, -1e30f, -1e30f};
    float lst[4] = {0.f, 0.f, 0.f, 0.f};

    stage(0, 0);

    for (int kt = 0; kt < 128; kt++) {
        int cur = kt & 1;
        __syncthreads();                 // drain own tile-kt loads + sync block
        if (kt < 127) stage(1 - cur, kt + 1);   // overlaps compute below

        const bf16_t* kl = kbuf + cur * 16384;
        const bf16_t* vl = vbuf + cur * 16384;

        // ---- S = Q K^T (16 rows x 32 keys), K from LDS fragment-major ----
        f32x4 s0 = {}, s1 = {};
        #pragma unroll
        for (int ks = 0; ks < 16; ks++) {
            bf16x8 k0 = ld8(kl + (ks * 2 + 0) * 512 + lane * 8);
            bf16x8 k1 = ld8(kl + (ks * 2 + 1) * 512 + lane * 8);
            s0 = mfma16(qf[ks], k0, s0);
            s1 = mfma16(qf[ks], k1, s1);
        }

        // ---- online softmax (row = quad*4+i, cols on the 16 lrow lanes) ----
        float p0[4], p1[4], alpha[4];
        #pragma unroll
        for (int i = 0; i < 4; i++) {
            float v0 = s0[i], v1 = s1[i];
            float mx = fmaxf(v0, v1);
            #pragma unroll
            for (int d = 8; d >= 1; d >>= 1) mx = fmaxf(mx, __shfl_xor(mx, d));
            float mnew = fmaxf(mst[i], mx);
            alpha[i] = __expf(mst[i] - mnew);
            p0[i] = __expf(v0 - mnew);
            p1[i] = __expf(v1 - mnew);
            float rsum = p0[i] + p1[i];
            #pragma unroll
            for (int d = 8; d >= 1; d >>= 1) rsum += __shfl_xor(rsum, d);
            lst[i] = lst[i] * alpha[i] + rsum;
            mst[i] = mnew;
        }
        #pragma unroll
        for (int n = 0; n < 16; n++)
            #pragma unroll
            for (int i = 0; i < 4; i++) acc[n][i] *= alpha[i];

        // ---- P: C-layout -> A-layout via wave-private LDS (no barrier) ----
        #pragma unroll
        for (int i = 0; i < 4; i++) {
            pw[(quad * 4 + i) * 32 + lrow]      = (bf16_t)p0[i];
            pw[(quad * 4 + i) * 32 + 16 + lrow] = (bf16_t)p1[i];
        }
        bf16x8 pf = ld8(pw + lrow * 32 + quad * 8);

        // ---- O += P V over this wave's 256 channels (16 n-tiles) ----
        #pragma unroll
        for (int nv = 0; nv < 16; nv++) {
            bf16x8 vf = ld8(vl + (size_t)(half * 256 + nv * 16 + lrow) * 32
                               + quad * 8);
            acc[nv] = mfma16(pf, vf, acc[nv]);
        }
    }

    // ---- normalize and store bf16 row-major ----
    float inv[4];
    #pragma unroll
    for (int i = 0; i < 4; i++) inv[i] = 1.0f / lst[i];
    #pragma unroll
    for (int nv = 0; nv < 16; nv++) {
        int c = half * 256 + nv * 16 + lrow;
        #pragma unroll
        for (int i = 0; i < 4; i++) {
            O[(qbase + rg * 16 + quad * 4 + i) * C512 + c] =
                (bf16_t)(acc[nv][i] * inv[i]);
        }
    }
}

// ---------------------------------------------------------------------------
extern "C" void kernel_launch(void* const* d_in, const int* in_sizes, int n_in,
                              void* d_out, int out_size, void* d_ws, size_t ws_size,
                              hipStream_t stream) {
    const float* x     = (const float*)d_in[0];
    const float* gamma = (const float*)d_in[1];
    const float* beta  = (const float*)d_in[2];
    const float* wq = (const float*)d_in[3];  const float* bq = (const float*)d_in[4];
    const float* wk = (const float*)d_in[5];  const float* bk = (const float*)d_in[6];
    const float* wv = (const float*)d_in[7];  const float* bv = (const float*)d_in[8];
    const float* wp = (const float*)d_in[9];  const float* bp = (const float*)d_in[10];
    float* out = (float*)d_out;

    char* ws = (char*)d_ws;
    size_t off = 0;
    float* stats = (float*)(ws + off);            off += 1024;
    bf16_t* xn   = (bf16_t*)(ws + off);           off += (size_t)NPIX * C512 * 2;
    bf16_t* wqT  = (bf16_t*)(ws + off);           off += (size_t)C512 * C512 * 2;
    bf16_t* wkT  = (bf16_t*)(ws + off);           off += (size_t)C512 * C512 * 2;
    bf16_t* wvT  = (bf16_t*)(ws + off);           off += (size_t)C512 * C512 * 2;
    bf16_t* wpT  = (bf16_t*)(ws + off);           off += (size_t)C512 * C512 * 2;
    bf16_t* Qb   = (bf16_t*)(ws + off);           off += (size_t)NPIX * C512 * 2;
    bf16_t* Kb   = (bf16_t*)(ws + off);           off += (size_t)NPIX * C512 * 2;
    bf16_t* VTb  = (bf16_t*)(ws + off);           off += (size_t)NPIX * C512 * 2;
    bf16_t* Ob   = (bf16_t*)(ws + off);           off += (size_t)NPIX * C512 * 2;

    gn_stats_k<<<64, 256, 0, stream>>>(x, stats);
    wt_conv_k<<<dim3(1024, 4), 256, 0, stream>>>(wq, wk, wv, wp, wqT, wkT, wvT, wpT);
    xn_k<<<4096, 256, 0, stream>>>(x, stats, gamma, beta, xn);

    dim3 ggrid(128, 8);
    // Q gets the folded softmax scale on its bias too
    gemm_k<0><<<ggrid, 256, 0, stream>>>(xn, wqT, bq, 0.044194173824159216f, nullptr, Qb);
    gemm_k<0><<<ggrid, 256, 0, stream>>>(xn, wkT, bk, 1.0f, nullptr, Kb);
    gemm_k<1><<<ggrid, 256, 0, stream>>>(xn, wvT, bv, 1.0f, nullptr, VTb);

    attn_k<<<256, 256, ATTN_LDS_BYTES, stream>>>(Qb, Kb, VTb, Ob);

    gemm_k<2><<<ggrid, 256, 0, stream>>>(Ob, wpT, bp, 1.0f, x, out);
}

// Round 3
// 578.139 us; speedup vs baseline: 3.2783x; 1.0882x over previous
//
#include <hip/hip_runtime.h>

// ---------------------------------------------------------------------------
// AttentionBlock: GroupNorm(32) -> q,k,v = xn@W+b -> softmax(q k^T / sqrt(C)) v
//                 -> out@wp+bp + x.   B=2, H=W=64, C=512, S=4096 per batch.
// Round 3: occupancy + chain fixes for attn (was 423 us at 1 wave/SIMD).
//   - split-K x2 -> 512 blocks; K-only LDS dbuf (69 KB) -> 2 blocks/CU.
//   - V read direct from global (lane-contiguous ld8 from VT, L1/L2).
//   - row-sum via ones-MFMA (no sum shuffles); alpha-rescale skipped via
//     wave-uniform __any when running max unchanged (exact).
//   - P LDS stride 40 elems: quads hit distinct bank groups (was 8-way).
//   - XCD swizzle: blocks sharing a (batch,ksplit) K/V stream on one XCD.
//   - combine kernel merges the 2 partials (unnormalized acc + m,l).
//   - QKV fused into one N=1536 GEMM.
// ---------------------------------------------------------------------------

typedef __bf16 bf16_t;
typedef __bf16 bf16x8 __attribute__((ext_vector_type(8)));
typedef __bf16 bf16x4 __attribute__((ext_vector_type(4)));
typedef float  f32x4  __attribute__((ext_vector_type(4)));

__device__ __forceinline__ bf16x8 ld8(const bf16_t* p) {
    return *reinterpret_cast<const bf16x8*>(p);
}
__device__ __forceinline__ f32x4 mfma16(bf16x8 a, bf16x8 b, f32x4 c) {
    return __builtin_amdgcn_mfma_f32_16x16x32_bf16(a, b, c, 0, 0, 0);
}
__device__ __forceinline__ void gload16(const bf16_t* gp, bf16_t* lp) {
    // HW semantics: LDS dest = uniform base + laneid*16B; gp is per-lane.
    __builtin_amdgcn_global_load_lds(
        (const __attribute__((address_space(1))) void*)gp,
        (__attribute__((address_space(3))) void*)lp, 16, 0, 0);
}

#define NPIX 8192      // B*H*W
#define C512 512
#define SEQ  4096      // H*W per batch
#define QSCALE 0.044194173824159216f   // 512^-0.5
#define KTILES 64      // 32-key tiles per split (2048 keys per split)

// ---------------- GroupNorm stats: one block per (b,g), 64 blocks -----------
__global__ __launch_bounds__(256) void gn_stats_k(const float* __restrict__ x,
                                                  float* __restrict__ stats) {
    int bg = blockIdx.x;               // b*32+g
    int b  = bg >> 5, g = bg & 31;
    const float* xp = x + (size_t)b * SEQ * C512 + g * 16;
    float s = 0.f, s2 = 0.f;
    for (int p = threadIdx.x; p < SEQ; p += 256) {
        const float4* q = reinterpret_cast<const float4*>(xp + (size_t)p * C512);
        #pragma unroll
        for (int i = 0; i < 4; i++) {
            float4 v = q[i];
            s  += v.x + v.y + v.z + v.w;
            s2 += v.x*v.x + v.y*v.y + v.z*v.z + v.w*v.w;
        }
    }
    #pragma unroll
    for (int off = 32; off >= 1; off >>= 1) {
        s  += __shfl_down(s, off);
        s2 += __shfl_down(s2, off);
    }
    __shared__ float rs[4], rs2[4];
    int wave = threadIdx.x >> 6;
    if ((threadIdx.x & 63) == 0) { rs[wave] = s; rs2[wave] = s2; }
    __syncthreads();
    if (threadIdx.x == 0) {
        float S = 0.f, S2 = 0.f;
        for (int i = 0; i < 4; i++) { S += rs[i]; S2 += rs2[i]; }
        float mean = S * (1.f / 65536.f);
        float var  = S2 * (1.f / 65536.f) - mean * mean;
        stats[bg * 2]     = mean;
        stats[bg * 2 + 1] = rsqrtf(var + 1e-5f);
    }
}

// ---------------- weights: fp32 (k,n) -> bf16 transposed (n,k) --------------
// y=0..2 -> wqkvT rows [y*512, y*512+512); y=0 (wq) folded with QSCALE.
// y=3 -> wpT.
__global__ __launch_bounds__(256) void wt_conv_k(const float* wq, const float* wk,
                                                 const float* wv, const float* wp,
                                                 bf16_t* wqkvT, bf16_t* wpT) {
    int y = blockIdx.y;
    const float* w = (y == 0) ? wq : (y == 1) ? wk : (y == 2) ? wv : wp;
    float scale = (y == 0) ? QSCALE : 1.0f;
    int tid = blockIdx.x * 256 + threadIdx.x;     // 262144 total
    int n = tid >> 9, k = tid & 511;
    bf16_t val = (bf16_t)(w[(size_t)k * C512 + n] * scale);
    if (y < 3) wqkvT[((size_t)y * C512 + n) * C512 + k] = val;
    else       wpT[(size_t)n * C512 + k] = val;
}

// ---------------- xn = groupnorm(x)*gamma+beta -> bf16 ----------------------
__global__ __launch_bounds__(256) void xn_k(const float* __restrict__ x,
                                            const float* __restrict__ stats,
                                            const float* __restrict__ gamma,
                                            const float* __restrict__ beta,
                                            bf16_t* __restrict__ xn) {
    size_t idx = ((size_t)blockIdx.x * 256 + threadIdx.x) * 4;   // elem index
    int c = (int)(idx & 511);
    size_t pix = idx >> 9;
    int b = (int)(pix >> 12);
    int g = c >> 4;
    float mean = stats[(b * 32 + g) * 2];
    float rstd = stats[(b * 32 + g) * 2 + 1];
    float4 v  = *reinterpret_cast<const float4*>(x + idx);
    float4 gm = *reinterpret_cast<const float4*>(gamma + c);
    float4 bt = *reinterpret_cast<const float4*>(beta + c);
    bf16x4 o;
    o[0] = (bf16_t)((v.x - mean) * rstd * gm.x + bt.x);
    o[1] = (bf16_t)((v.y - mean) * rstd * gm.y + bt.y);
    o[2] = (bf16_t)((v.z - mean) * rstd * gm.z + bt.z);
    o[3] = (bf16_t)((v.w - mean) * rstd * gm.w + bt.w);
    *reinterpret_cast<bf16x4*>(xn + idx) = o;
}

// ---------------- fused QKV GEMM: D(8192,1536) = xn x wqkvT^T + bias --------
// n-range 0-511 -> Q (bf16 row-major), 512-1023 -> K (row-major),
// 1024-1535 -> V stored transposed per batch vt[b][c][s].
__global__ __launch_bounds__(256) void gemm_qkv_k(const bf16_t* __restrict__ A,
                                                  const bf16_t* __restrict__ WT,
                                                  const float* __restrict__ bq,
                                                  const float* __restrict__ bk,
                                                  const float* __restrict__ bv,
                                                  bf16_t* __restrict__ Qb,
                                                  bf16_t* __restrict__ Kb,
                                                  bf16_t* __restrict__ VTb) {
    int lane = threadIdx.x & 63;
    int w    = threadIdx.x >> 6;          // 4 waves, 2x2
    int lrow = lane & 15, quad = lane >> 4;
    int mbase = blockIdx.x * 64 + (w & 1) * 32;
    int nbase = blockIdx.y * 64 + (w >> 1) * 32;

    f32x4 acc[2][2] = {};
    const bf16_t* a0p = A  + (size_t)(mbase + lrow) * C512 + quad * 8;
    const bf16_t* a1p = a0p + 16 * C512;
    const bf16_t* b0p = WT + (size_t)(nbase + lrow) * C512 + quad * 8;
    const bf16_t* b1p = b0p + 16 * C512;

    #pragma unroll 4
    for (int kk = 0; kk < 16; kk++) {
        bf16x8 a0 = ld8(a0p + kk * 32);
        bf16x8 a1 = ld8(a1p + kk * 32);
        bf16x8 b0 = ld8(b0p + kk * 32);
        bf16x8 b1 = ld8(b1p + kk * 32);
        acc[0][0] = mfma16(a0, b0, acc[0][0]);
        acc[0][1] = mfma16(a0, b1, acc[0][1]);
        acc[1][0] = mfma16(a1, b0, acc[1][0]);
        acc[1][1] = mfma16(a1, b1, acc[1][1]);
    }

    #pragma unroll
    for (int mi = 0; mi < 2; mi++) {
        #pragma unroll
        for (int ni = 0; ni < 2; ni++) {
            int colG = nbase + ni * 16 + lrow;
            int seg = colG >> 9, col = colG & 511;
            const float* bias = (seg == 0) ? bq : (seg == 1) ? bk : bv;
            float bvv = bias[col] * ((seg == 0) ? QSCALE : 1.0f);
            int rowb = mbase + mi * 16 + quad * 4;
            #pragma unroll
            for (int i = 0; i < 4; i++) {
                int row = rowb + i;
                bf16_t val = (bf16_t)(acc[mi][ni][i] + bvv);
                if (seg == 0) {
                    Qb[(size_t)row * C512 + col] = val;
                } else if (seg == 1) {
                    Kb[(size_t)row * C512 + col] = val;
                } else {
                    int b = row >> 12, s = row & 4095;
                    VTb[((size_t)(b * C512 + col)) * SEQ + s] = val;
                }
            }
        }
    }
}

// ---------------- out-projection GEMM + residual ----------------------------
__global__ __launch_bounds__(256) void gemm_out_k(const bf16_t* __restrict__ A,
                                                  const bf16_t* __restrict__ WT,
                                                  const float* __restrict__ bias,
                                                  const float* __restrict__ resid,
                                                  float* __restrict__ outp) {
    int lane = threadIdx.x & 63;
    int w    = threadIdx.x >> 6;
    int lrow = lane & 15, quad = lane >> 4;
    int mbase = blockIdx.x * 64 + (w & 1) * 32;
    int nbase = blockIdx.y * 64 + (w >> 1) * 32;

    f32x4 acc[2][2] = {};
    const bf16_t* a0p = A  + (size_t)(mbase + lrow) * C512 + quad * 8;
    const bf16_t* a1p = a0p + 16 * C512;
    const bf16_t* b0p = WT + (size_t)(nbase + lrow) * C512 + quad * 8;
    const bf16_t* b1p = b0p + 16 * C512;

    #pragma unroll 4
    for (int kk = 0; kk < 16; kk++) {
        bf16x8 a0 = ld8(a0p + kk * 32);
        bf16x8 a1 = ld8(a1p + kk * 32);
        bf16x8 b0 = ld8(b0p + kk * 32);
        bf16x8 b1 = ld8(b1p + kk * 32);
        acc[0][0] = mfma16(a0, b0, acc[0][0]);
        acc[0][1] = mfma16(a0, b1, acc[0][1]);
        acc[1][0] = mfma16(a1, b0, acc[1][0]);
        acc[1][1] = mfma16(a1, b1, acc[1][1]);
    }

    #pragma unroll
    for (int mi = 0; mi < 2; mi++) {
        #pragma unroll
        for (int ni = 0; ni < 2; ni++) {
            int col = nbase + ni * 16 + lrow;
            float bvv = bias[col];
            int rowb = mbase + mi * 16 + quad * 4;
            #pragma unroll
            for (int i = 0; i < 4; i++) {
                size_t idx = (size_t)(rowb + i) * C512 + col;
                outp[idx] = acc[mi][ni][i] + bvv + resid[idx];
            }
        }
    }
}

// ---------------- flash attention v3 (split-K x2) ---------------------------
// Grid 512 blocks: (batch, ksplit, qtile) XCD-swizzled so blocks sharing a
// K/V stream sit on one XCD. Block = 4 waves: rg = 16 q-rows, half = 256 chs.
// K staged in LDS (fragment-major, dbuf). V read direct from global VT.
// Output: unnormalized acc (bf16) + per-row (m,l) for the combine pass.
__global__ __launch_bounds__(256, 2) void attn_k(const bf16_t* __restrict__ Q,
                                                 const bf16_t* __restrict__ K,
                                                 const bf16_t* __restrict__ VT,
                                                 bf16_t* __restrict__ Op0,
                                                 bf16_t* __restrict__ Op1,
                                                 float2* __restrict__ ml) {
    __shared__ bf16_t kbuf[2 * 16384];   // 64 KB: K-tile dbuf
    __shared__ bf16_t pbuf[4 * 640];     // 5 KB: per-wave P, row stride 40

    int lane = threadIdx.x & 63;
    int w    = threadIdx.x >> 6;
    int rg   = w >> 1, half = w & 1;
    int lrow = lane & 15, quad = lane >> 4;

    // XCD swizzle: assume xcd = blockIdx.x & 7. 3 bits: b, sp, q-hi.
    int xcd  = blockIdx.x & 7;
    int slot = blockIdx.x >> 3;          // 0..63
    int b  = (xcd >> 2) & 1;
    int sp = (xcd >> 1) & 1;
    int qt = ((xcd & 1) << 6) | slot;    // 0..127

    size_t qbase = (size_t)b * SEQ + qt * 32;
    const bf16_t* Kb = K + ((size_t)b * SEQ + sp * 2048) * C512;
    const bf16_t* Vg = VT + ((size_t)(b * C512 + half * 256 + lrow)) * SEQ
                          + sp * 2048 + quad * 8;
    bf16_t* pw = pbuf + w * 640;

    // Q fragments for this wave's 16 rows (QSCALE folded into wq/bq)
    bf16x8 qf[16];
    {
        const bf16_t* qp = Q + (qbase + rg * 16 + lrow) * C512 + quad * 8;
        #pragma unroll
        for (int kk = 0; kk < 16; kk++) qf[kk] = ld8(qp + kk * 32);
    }

    // stage K-tile kt into dbuf half `buf` (fragment-major; 8 chunks/wave)
    auto stageK = [&](int buf, int kt) {
        bf16_t* kd = kbuf + buf * 16384;
        #pragma unroll
        for (int ii = 0; ii < 8; ii++) {
            int i = w * 8 + ii;                      // chunk-instr 0..31
            int kk = i >> 1, nt = i & 1;
            const bf16_t* gp = Kb + (size_t)(kt * 32 + nt * 16 + lrow) * C512
                                  + kk * 32 + quad * 8;
            gload16(gp, kd + i * 512);
        }
    };

    f32x4 acc[16] = {};                  // 16 rows x 256 chs (unnormalized)
    float mst[4] = {-1e30f, -1e30f, -1e30f, -1e30f};
    float lst[4] = {0.f, 0.f, 0.f, 0.f};
    bf16x8 onesf;
    #pragma unroll
    for (int j = 0; j < 8; j++) onesf[j] = (bf16_t)1.0f;

    stageK(0, 0);

    for (int kt = 0; kt < KTILES; kt++) {
        int cur = kt & 1;
        __syncthreads();                 // stage(kt) complete; prev reads done
        if (kt + 1 < KTILES) stageK(1 - cur, kt + 1);   // overlaps compute

        const bf16_t* kl = kbuf + cur * 16384;

        // ---- S = Q K^T (16 rows x 32 keys) ----
        f32x4 s0 = {}, s1 = {};
        #pragma unroll
        for (int kk = 0; kk < 16; kk++) {
            s0 = mfma16(qf[kk], ld8(kl + (kk * 2 + 0) * 512 + lane * 8), s0);
            s1 = mfma16(qf[kk], ld8(kl + (kk * 2 + 1) * 512 + lane * 8), s1);
        }

        // ---- online softmax: max via shuffles, sum via ones-MFMA below ----
        float p0[4], p1[4], alpha[4];
        #pragma unroll
        for (int i = 0; i < 4; i++) {
            float v0 = s0[i], v1 = s1[i];
            float mx = fmaxf(v0, v1);
            #pragma unroll
            for (int d = 8; d >= 1; d >>= 1) mx = fmaxf(mx, __shfl_xor(mx, d));
            float mnew = fmaxf(mst[i], mx);
            alpha[i] = __expf(mst[i] - mnew);
            p0[i] = __expf(v0 - mnew);
            p1[i] = __expf(v1 - mnew);
            mst[i] = mnew;
        }
        // rescale acc only if some row's max moved (exact: alpha==1 else)
        float am = fminf(fminf(alpha[0], alpha[1]), fminf(alpha[2], alpha[3]));
        if (__any(am < 1.0f)) {
            #pragma unroll
            for (int n = 0; n < 16; n++)
                #pragma unroll
                for (int i = 0; i < 4; i++) acc[n][i] *= alpha[i];
        }

        // ---- P: C-layout -> A-layout via wave-private LDS (stride 40) ----
        #pragma unroll
        for (int i = 0; i < 4; i++) {
            pw[(quad * 4 + i) * 40 + lrow]      = (bf16_t)p0[i];
            pw[(quad * 4 + i) * 40 + 16 + lrow] = (bf16_t)p1[i];
        }
        bf16x8 pf = ld8(pw + lrow * 40 + quad * 8);

        // row-sums of P via ones-MFMA (replaces 16 shuffle ops)
        f32x4 lz = {};
        f32x4 lrs = mfma16(pf, onesf, lz);

        // ---- O += P V, V direct from global (lane-contiguous ld8) ----
        const bf16_t* vp = Vg + kt * 32;
        #pragma unroll
        for (int nv = 0; nv < 16; nv++)
            acc[nv] = mfma16(pf, ld8(vp + (size_t)nv * 16 * SEQ), acc[nv]);

        #pragma unroll
        for (int i = 0; i < 4; i++) lst[i] = lst[i] * alpha[i] + lrs[i];
    }

    // ---- store unnormalized partial + (m,l) ----
    bf16_t* op = (sp == 0 ? Op0 : Op1) + (qbase + rg * 16) * C512;
    #pragma unroll
    for (int nv = 0; nv < 16; nv++) {
        int c = half * 256 + nv * 16 + lrow;
        #pragma unroll
        for (int i = 0; i < 4; i++)
            op[(size_t)(quad * 4 + i) * C512 + c] = (bf16_t)acc[nv][i];
    }
    if (half == 0 && lrow == 0) {
        #pragma unroll
        for (int i = 0; i < 4; i++)
            ml[(size_t)sp * NPIX + qbase + rg * 16 + quad * 4 + i] =
                make_float2(mst[i], lst[i]);
    }
}

// ---------------- combine the two split-K partials --------------------------
__global__ __launch_bounds__(256) void attn_combine_k(const bf16_t* __restrict__ Op0,
                                                      const bf16_t* __restrict__ Op1,
                                                      const float2* __restrict__ ml,
                                                      bf16_t* __restrict__ O) {
    int idx = blockIdx.x * 256 + threadIdx.x;    // 524288 threads
    int row = idx >> 6;
    int c8  = (idx & 63) << 3;
    float2 s0 = ml[row], s1 = ml[NPIX + row];
    float m  = fmaxf(s0.x, s1.x);
    float a0 = __expf(s0.x - m);
    float a1 = __expf(s1.x - m);
    float inv = 1.0f / (a0 * s0.y + a1 * s1.y);
    a0 *= inv; a1 *= inv;
    bf16x8 o0 = ld8(Op0 + (size_t)row * C512 + c8);
    bf16x8 o1 = ld8(Op1 + (size_t)row * C512 + c8);
    bf16x8 o;
    #pragma unroll
    for (int j = 0; j < 8; j++)
        o[j] = (bf16_t)(a0 * (float)o0[j] + a1 * (float)o1[j]);
    *reinterpret_cast<bf16x8*>(O + (size_t)row * C512 + c8) = o;
}

// ---------------------------------------------------------------------------
extern "C" void kernel_launch(void* const* d_in, const int* in_sizes, int n_in,
                              void* d_out, int out_size, void* d_ws, size_t ws_size,
                              hipStream_t stream) {
    const float* x     = (const float*)d_in[0];
    const float* gamma = (const float*)d_in[1];
    const float* beta  = (const float*)d_in[2];
    const float* wq = (const float*)d_in[3];  const float* bq = (const float*)d_in[4];
    const float* wk = (const float*)d_in[5];  const float* bk = (const float*)d_in[6];
    const float* wv = (const float*)d_in[7];  const float* bv = (const float*)d_in[8];
    const float* wp = (const float*)d_in[9];  const float* bp = (const float*)d_in[10];
    float* out = (float*)d_out;

    char* ws = (char*)d_ws;
    size_t off = 0;
    float*  stats  = (float*)(ws + off);   off += 1024;
    bf16_t* xn     = (bf16_t*)(ws + off);  off += (size_t)NPIX * C512 * 2;  // later Op0
    bf16_t* wqkvT  = (bf16_t*)(ws + off);  off += (size_t)3 * C512 * C512 * 2;
    bf16_t* wpT    = (bf16_t*)(ws + off);  off += (size_t)C512 * C512 * 2;
    bf16_t* Qb     = (bf16_t*)(ws + off);  off += (size_t)NPIX * C512 * 2;  // later Ob
    bf16_t* Kb     = (bf16_t*)(ws + off);  off += (size_t)NPIX * C512 * 2;
    bf16_t* VTb    = (bf16_t*)(ws + off);  off += (size_t)NPIX * C512 * 2;
    bf16_t* Op1    = (bf16_t*)(ws + off);  off += (size_t)NPIX * C512 * 2;
    float2* ml     = (float2*)(ws + off);  off += (size_t)2 * NPIX * sizeof(float2);
    bf16_t* Op0 = xn;     // xn is dead after gemm_qkv_k
    bf16_t* Ob  = Qb;     // Q is dead after attn_k

    gn_stats_k<<<64, 256, 0, stream>>>(x, stats);
    wt_conv_k<<<dim3(1024, 4), 256, 0, stream>>>(wq, wk, wv, wp, wqkvT, wpT);
    xn_k<<<4096, 256, 0, stream>>>(x, stats, gamma, beta, xn);

    gemm_qkv_k<<<dim3(128, 24), 256, 0, stream>>>(xn, wqkvT, bq, bk, bv, Qb, Kb, VTb);

    attn_k<<<512, 256, 0, stream>>>(Qb, Kb, VTb, Op0, Op1, ml);
    attn_combine_k<<<2048, 256, 0, stream>>>(Op0, Op1, ml, Ob);

    gemm_out_k<<<dim3(128, 8), 256, 0, stream>>>(Ob, wpT, bp, x, out);
}